// Round 1
// baseline (272.157 us; speedup 1.0000x reference)
//
#include <hip/hip_runtime.h>
#include <math.h>

#define NBB 128
#define NAA 5
#define NCC 80
#define NHH 28
#define NWW 28
#define NTT 50
#define CH  85            // 5 + NC
#define HW  784           // NH*NW
#define CELLS 3920        // NA*NH*NW
#define NREC  6400        // NB*NT

__constant__ float c_AW[5] = {2.8f, 5.1f, 6.4f, 9.2f, 14.1f};
__constant__ float c_AH[5] = {4.8f, 10.2f, 16.3f, 19.8f, 23.7f};

__device__ __forceinline__ float sigmoidf_(float x) {
    return 1.0f / (1.0f + __expf(-x));
}

__device__ __forceinline__ float smooth_l1(float d) {
    float ad = fabsf(d);
    return (ad < 1.0f) ? 0.5f * d * d : ad - 0.5f;
}

// ---------------------------------------------------------------------------
// Pass 1: one block per batch, one thread per gt target.
// Computes best anchor, assigned cell, tx/ty/tw/th/tconf/tcls; resolves
// duplicate cells with last-wins (matching numpy scatter semantics).
// ---------------------------------------------------------------------------
__global__ __launch_bounds__(64) void prep_targets(
    const float* __restrict__ out, const float* __restrict__ tgt,
    int* __restrict__ recIdx, float* __restrict__ recF)
{
    const int b = blockIdx.x;
    const int t = threadIdx.x;
    __shared__ int cellS[64];

    int   cell = -1;
    float tx = 0.f, ty = 0.f, tw = 0.f, th = 0.f, tconf = 0.f, tcls = 0.f;

    if (t < NTT) {
        const float* tp = tgt + b * NTT * 5 + t * 5;
        float cls = tp[0];
        float gx = tp[1] * NWW;
        float gy = tp[2] * NHH;
        float gw = tp[3] * NWW;
        float gh = tp[4] * NHH;
        float ga = gw * gh;

        // best anchor: IoU of (0,0,gw,gh) vs (0,0,aw,ah) -> inter=min*min
        int best = 0; float bestI = -1.0f;
        for (int a = 0; a < 5; ++a) {
            float inter = fminf(gw, c_AW[a]) * fminf(gh, c_AH[a]);
            float uni   = ga + c_AW[a] * c_AH[a] - inter;
            float iou   = inter / uni;
            if (iou > bestI) { bestI = iou; best = a; }
        }
        int gi = (int)floorf(gx);
        int gj = (int)floorf(gy);
        cell = (best * NHH + gj) * NWW + gi;

        // assigned predicted box straight from output
        const float* op = out + ((size_t)(b * NAA + best) * CH) * HW + gj * NWW + gi;
        float px = sigmoidf_(op[0])      + (float)gi;
        float py = sigmoidf_(op[HW])     + (float)gj;
        float pw = __expf(op[2 * HW]) * c_AW[best];
        float ph = __expf(op[3 * HW]) * c_AH[best];

        float mx = fminf(px - pw * 0.5f, gx - gw * 0.5f);
        float Mx = fmaxf(px + pw * 0.5f, gx + gw * 0.5f);
        float my = fminf(py - ph * 0.5f, gy - gh * 0.5f);
        float My = fmaxf(py + ph * 0.5f, gy + gh * 0.5f);
        float cw  = pw + gw - (Mx - mx);
        float chh = ph + gh - (My - my);
        float inter = (cw > 0.f && chh > 0.f) ? cw * chh : 0.f;
        float uni   = pw * ph + ga - inter;

        tconf = inter / uni;
        tx = gx - (float)gi;
        ty = gy - (float)gj;
        tw = __logf(gw / c_AW[best]);
        th = __logf(gh / c_AH[best]);
        tcls = cls;
    }

    cellS[t] = cell;
    __syncthreads();

    if (t < NTT) {
        bool active = true;
        for (int t2 = t + 1; t2 < NTT; ++t2)
            if (cellS[t2] == cell) active = false;   // a later record wins
        int r = b * NTT + t;
        recIdx[r]            = active ? cell : -1;
        recF[0 * NREC + r] = tx;
        recF[1 * NREC + r] = ty;
        recF[2 * NREC + r] = tw;
        recF[3 * NREC + r] = th;
        recF[4 * NREC + r] = tconf;
        recF[5 * NREC + r] = tcls;
    }
}

// ---------------------------------------------------------------------------
// Pass 2: confidence loss over all NB*NA*NH*NW cells.
// grid = (16, NB), block = 256. GT boxes + assignment records in LDS.
// max_iou > 0.6  <=>  1.6*inter > 0.6*(a1+a2)   (division-free)
// ---------------------------------------------------------------------------
__global__ __launch_bounds__(256) void conf_loss(
    const float* __restrict__ out, const float* __restrict__ tgt,
    const int* __restrict__ recIdx, const float* __restrict__ recTconf,
    float* __restrict__ d_out)
{
    __shared__ float L2[NTT], R2[NTT], T2[NTT], B2[NTT], AR[NTT];
    __shared__ int   rIdx[NTT];
    __shared__ float rTc[NTT];
    __shared__ float red[256];

    const int b   = blockIdx.y;
    const int tid = threadIdx.x;

    if (tid < NTT) {
        const float* tp = tgt + b * NTT * 5 + tid * 5;
        float gx = tp[1] * NWW, gy = tp[2] * NHH;
        float gw = tp[3] * NWW, gh = tp[4] * NHH;
        L2[tid] = gx - gw * 0.5f;
        R2[tid] = gx + gw * 0.5f;
        T2[tid] = gy - gh * 0.5f;
        B2[tid] = gy + gh * 0.5f;
        AR[tid] = gw * gh;
    } else if (tid >= 64 && tid < 64 + NTT) {
        int j = tid - 64;
        rIdx[j] = recIdx[b * NTT + j];
        rTc[j]  = recTconf[b * NTT + j];
    }
    __syncthreads();

    const int cell = blockIdx.x * 256 + tid;
    float term = 0.0f;

    if (cell < CELLS) {
        int a  = cell / HW;
        int hw = cell - a * HW;
        int wi = hw % NWW;
        int hj = hw / NWW;
        const float* op = out + ((size_t)(b * NAA + a) * CH) * HW + hw;

        float px   = sigmoidf_(op[0])  + (float)wi;
        float py   = sigmoidf_(op[HW]) + (float)hj;
        float pw   = __expf(op[2 * HW]) * c_AW[a];
        float ph   = __expf(op[3 * HW]) * c_AH[a];
        float conf = sigmoidf_(op[4 * HW]);

        float l1 = px - pw * 0.5f, r1 = px + pw * 0.5f;
        float t1 = py - ph * 0.5f, b1 = py + ph * 0.5f;
        float a1 = pw * ph;

        bool flag = false;
        #pragma unroll 5
        for (int j = 0; j < NTT; ++j) {
            float cw  = fminf(r1, R2[j]) - fmaxf(l1, L2[j]);
            float chh = fminf(b1, B2[j]) - fmaxf(t1, T2[j]);
            float inter = (cw > 0.f && chh > 0.f) ? cw * chh : 0.f;
            flag = flag || (inter * 1.6f > 0.6f * (a1 + AR[j]));
        }

        bool assigned = false; float tc = 0.f;
        for (int j = 0; j < NTT; ++j) {
            if (rIdx[j] == cell) { assigned = true; tc = rTc[j]; }
        }

        if (assigned) { float d = conf - tc; term = 2.5f * d * d; }
        else if (!flag) { term = 0.5f * conf * conf; }
    }

    red[tid] = term;
    __syncthreads();
    for (int s = 128; s > 0; s >>= 1) {
        if (tid < s) red[tid] += red[tid + s];
        __syncthreads();
    }
    if (tid == 0) atomicAdd(d_out, red[0]);
}

// ---------------------------------------------------------------------------
// Pass 3: coord smooth-L1 + focal class loss at assigned cells.
// One wave per 4 records; lanes cover the 80 class logits (lane + lane+64).
// ---------------------------------------------------------------------------
__global__ __launch_bounds__(64) void assigned_loss(
    const float* __restrict__ out, const int* __restrict__ recIdx,
    const float* __restrict__ recF, float* __restrict__ d_out)
{
    const int lane = threadIdx.x;
    float acc = 0.0f;

    for (int k = 0; k < 4; ++k) {
        int r = blockIdx.x * 4 + k;
        int cell = recIdx[r];           // wave-uniform broadcast load
        if (cell < 0) continue;
        int b  = r / NTT;
        int a  = cell / HW;
        int hw = cell - a * HW;
        const float* op = out + ((size_t)(b * NAA + a) * CH) * HW + hw;

        // class logits: lane -> c=lane, and c=lane+64 for lane<16
        float l0 = op[(5 + lane) * HW];
        float l1 = (lane < 16) ? op[(5 + 64 + lane) * HW] : -INFINITY;

        float m = fmaxf(l0, l1);
        for (int o = 32; o >= 1; o >>= 1) m = fmaxf(m, __shfl_xor(m, o));
        float s = __expf(l0 - m) + ((lane < 16) ? __expf(l1 - m) : 0.0f);
        for (int o = 32; o >= 1; o >>= 1) s += __shfl_xor(s, o);

        int t = (int)recF[5 * NREC + r];          // tcls, wave-uniform
        float lt = (t < 64) ? __shfl(l0, t) : __shfl(l1, t - 64);
        float logpt = lt - m - __logf(s);
        float pt = __expf(logpt);
        float focal = -(1.0f - pt) * (1.0f - pt) * logpt;

        if (lane == 0) {
            float tx = recF[0 * NREC + r];
            float ty = recF[1 * NREC + r];
            float tw = recF[2 * NREC + r];
            float th = recF[3 * NREC + r];
            float x = sigmoidf_(op[0]);
            float y = sigmoidf_(op[HW]);
            float w = op[2 * HW];
            float h = op[3 * HW];
            acc += focal;
            acc += 0.5f * (smooth_l1(x - tx) + smooth_l1(y - ty) +
                           smooth_l1(w - tw) + smooth_l1(h - th));
        }
    }
    if (lane == 0) atomicAdd(d_out, acc);
}

extern "C" void kernel_launch(void* const* d_in, const int* in_sizes, int n_in,
                              void* d_out, int out_size, void* d_ws, size_t ws_size,
                              hipStream_t stream) {
    const float* out_p = (const float*)d_in[0];   // (128, 425, 28, 28)
    const float* tgt_p = (const float*)d_in[1];   // (128, 250)
    float* loss = (float*)d_out;

    int*   recIdx = (int*)d_ws;                   // NREC ints
    float* recF   = (float*)d_ws + NREC;          // 6 * NREC floats

    hipMemsetAsync(loss, 0, (size_t)out_size * sizeof(float), stream);

    prep_targets<<<dim3(NBB), dim3(64), 0, stream>>>(out_p, tgt_p, recIdx, recF);
    conf_loss<<<dim3(16, NBB), dim3(256), 0, stream>>>(out_p, tgt_p, recIdx,
                                                       recF + 4 * NREC, loss);
    assigned_loss<<<dim3(NREC / 4), dim3(64), 0, stream>>>(out_p, recIdx, recF, loss);
}

// Round 2
// 267.497 us; speedup vs baseline: 1.0174x; 1.0174x over previous
//
#include <hip/hip_runtime.h>
#include <math.h>

#define NBB 128
#define NAA 5
#define NCC 80
#define NHH 28
#define NWW 28
#define NTT 50
#define CH  85            // 5 + NC
#define HW  784           // NH*NW
#define CELLS 3920        // NA*NH*NW
#define NREC  6400        // NB*NT

__constant__ float c_AW[5] = {2.8f, 5.1f, 6.4f, 9.2f, 14.1f};
__constant__ float c_AH[5] = {4.8f, 10.2f, 16.3f, 19.8f, 23.7f};

__device__ __forceinline__ float sigmoidf_(float x) {
    return 1.0f / (1.0f + __expf(-x));
}

__device__ __forceinline__ float smooth_l1(float d) {
    float ad = fabsf(d);
    return (ad < 1.0f) ? 0.5f * d * d : ad - 0.5f;
}

// ---------------------------------------------------------------------------
// Pass 1 (fused prep + conf loss): grid (16, NB), block 256.
// Threads 0..49 recompute the per-target records in LDS (cheap, redundant
// across the 16 x-blocks); blockIdx.x==0 blocks also write the deduped
// records to global for pass 2. Then all 256 threads evaluate the conf
// loss over cells. max_iou > 0.6  <=>  1.6*inter > 0.6*(a1+a2)  (no divide).
// ---------------------------------------------------------------------------
__global__ __launch_bounds__(256) void prep_conf_loss(
    const float* __restrict__ out, const float* __restrict__ tgt,
    int* __restrict__ recIdx, float* __restrict__ recF,
    float* __restrict__ d_out)
{
    __shared__ float L2[NTT], R2[NTT], T2[NTT], B2[NTT], AR[NTT];
    __shared__ int   rCell[NTT];
    __shared__ float rTc[NTT];
    __shared__ float red[256];

    const int b   = blockIdx.y;
    const int tid = threadIdx.x;

    float tx = 0.f, ty = 0.f, tw = 0.f, th = 0.f, tcls = 0.f;

    if (tid < NTT) {
        const float* tp = tgt + b * NTT * 5 + tid * 5;
        float cls = tp[0];
        float gx = tp[1] * NWW;
        float gy = tp[2] * NHH;
        float gw = tp[3] * NWW;
        float gh = tp[4] * NHH;
        float ga = gw * gh;

        L2[tid] = gx - gw * 0.5f;
        R2[tid] = gx + gw * 0.5f;
        T2[tid] = gy - gh * 0.5f;
        B2[tid] = gy + gh * 0.5f;
        AR[tid] = ga;

        // best anchor: IoU of (0,0,gw,gh) vs (0,0,aw,ah) -> inter = min*min
        int best = 0; float bestI = -1.0f;
        #pragma unroll
        for (int a = 0; a < 5; ++a) {
            float inter = fminf(gw, c_AW[a]) * fminf(gh, c_AH[a]);
            float uni   = ga + c_AW[a] * c_AH[a] - inter;
            float iou   = inter / uni;
            if (iou > bestI) { bestI = iou; best = a; }
        }
        int gi = (int)floorf(gx);
        int gj = (int)floorf(gy);
        int cell = (best * NHH + gj) * NWW + gi;

        // assigned predicted box (4 gathered loads)
        const float* op = out + ((size_t)(b * NAA + best) * CH) * HW + gj * NWW + gi;
        float px = sigmoidf_(op[0])      + (float)gi;
        float py = sigmoidf_(op[HW])     + (float)gj;
        float pw = __expf(op[2 * HW]) * c_AW[best];
        float ph = __expf(op[3 * HW]) * c_AH[best];

        float mx = fminf(px - pw * 0.5f, gx - gw * 0.5f);
        float Mx = fmaxf(px + pw * 0.5f, gx + gw * 0.5f);
        float my = fminf(py - ph * 0.5f, gy - gh * 0.5f);
        float My = fmaxf(py + ph * 0.5f, gy + gh * 0.5f);
        float cw  = pw + gw - (Mx - mx);
        float chh = ph + gh - (My - my);
        float inter = (cw > 0.f && chh > 0.f) ? cw * chh : 0.f;
        float uni   = pw * ph + ga - inter;

        rCell[tid] = cell;
        rTc[tid]   = inter / uni;

        tx = gx - (float)gi;
        ty = gy - (float)gj;
        tw = __logf(gw / c_AW[best]);
        th = __logf(gh / c_AH[best]);
        tcls = cls;
    }
    __syncthreads();

    // blockIdx.x==0 blocks publish deduped records for pass 2
    if (blockIdx.x == 0 && tid < NTT) {
        int cell = rCell[tid];
        bool active = true;
        for (int t2 = tid + 1; t2 < NTT; ++t2)
            if (rCell[t2] == cell) active = false;   // later record wins
        int r = b * NTT + tid;
        recIdx[r]          = active ? cell : -1;
        recF[0 * NREC + r] = tx;
        recF[1 * NREC + r] = ty;
        recF[2 * NREC + r] = tw;
        recF[3 * NREC + r] = th;
        recF[4 * NREC + r] = tcls;
    }

    // ---- conf loss over cells ----
    const int cell = blockIdx.x * 256 + tid;
    float term = 0.0f;

    if (cell < CELLS) {
        int a  = cell / HW;
        int hw = cell - a * HW;
        int wi = hw % NWW;
        int hj = hw / NWW;
        const float* op = out + ((size_t)(b * NAA + a) * CH) * HW + hw;

        float px   = sigmoidf_(op[0])  + (float)wi;
        float py   = sigmoidf_(op[HW]) + (float)hj;
        float pw   = __expf(op[2 * HW]) * c_AW[a];
        float ph   = __expf(op[3 * HW]) * c_AH[a];
        float conf = sigmoidf_(op[4 * HW]);

        float l1 = px - pw * 0.5f, r1 = px + pw * 0.5f;
        float t1 = py - ph * 0.5f, b1 = py + ph * 0.5f;
        float a1 = pw * ph;

        bool flag = false;
        #pragma unroll 5
        for (int j = 0; j < NTT; ++j) {
            float cw  = fminf(r1, R2[j]) - fmaxf(l1, L2[j]);
            float chh = fminf(b1, B2[j]) - fmaxf(t1, T2[j]);
            float inter = (cw > 0.f && chh > 0.f) ? cw * chh : 0.f;
            flag = flag || (inter * 1.6f > 0.6f * (a1 + AR[j]));
        }

        bool assigned = false; float tc = 0.f;
        for (int j = 0; j < NTT; ++j) {
            if (rCell[j] == cell) { assigned = true; tc = rTc[j]; }  // last wins
        }

        if (assigned) { float d = conf - tc; term = 2.5f * d * d; }
        else if (!flag) { term = 0.5f * conf * conf; }
    }

    red[tid] = term;
    __syncthreads();
    for (int s = 128; s > 0; s >>= 1) {
        if (tid < s) red[tid] += red[tid + s];
        __syncthreads();
    }
    if (tid == 0) atomicAdd(d_out, red[0]);
}

// ---------------------------------------------------------------------------
// Pass 2: coord smooth-L1 + focal class loss at assigned cells.
// One wave per record; 4 waves (4 records) per block; 1600 blocks.
// Lanes cover the 80 class logits (c = lane, and c = 64+lane for lane<16).
// ---------------------------------------------------------------------------
__global__ __launch_bounds__(256) void assigned_loss(
    const float* __restrict__ out, const int* __restrict__ recIdx,
    const float* __restrict__ recF, float* __restrict__ d_out)
{
    const int wave = threadIdx.x >> 6;
    const int lane = threadIdx.x & 63;
    const int r    = blockIdx.x * 4 + wave;

    __shared__ float ws[4];
    float contrib = 0.0f;

    int cell = recIdx[r];               // wave-uniform broadcast load
    if (cell >= 0) {
        int b  = r / NTT;
        int a  = cell / HW;
        int hw = cell - a * HW;
        const float* op = out + ((size_t)(b * NAA + a) * CH) * HW + hw;

        // class logits: lane -> c=lane, plus c=64+lane for lane<16
        float l0 = op[(5 + lane) * HW];
        float l1 = (lane < 16) ? op[(5 + 64 + lane) * HW] : -INFINITY;

        float m = fmaxf(l0, l1);
        for (int o = 32; o >= 1; o >>= 1) m = fmaxf(m, __shfl_xor(m, o));
        float s = __expf(l0 - m) + ((lane < 16) ? __expf(l1 - m) : 0.0f);
        for (int o = 32; o >= 1; o >>= 1) s += __shfl_xor(s, o);

        int t = (int)recF[4 * NREC + r];          // tcls, wave-uniform
        float lt = (t < 64) ? __shfl(l0, t) : __shfl(l1, t - 64);
        float logpt = lt - m - __logf(s);
        float pt = __expf(logpt);
        float focal = -(1.0f - pt) * (1.0f - pt) * logpt;

        if (lane == 0) {
            float tx = recF[0 * NREC + r];
            float ty = recF[1 * NREC + r];
            float tw = recF[2 * NREC + r];
            float th = recF[3 * NREC + r];
            float x = sigmoidf_(op[0]);
            float y = sigmoidf_(op[HW]);
            float w = op[2 * HW];
            float h = op[3 * HW];
            contrib = focal +
                      0.5f * (smooth_l1(x - tx) + smooth_l1(y - ty) +
                              smooth_l1(w - tw) + smooth_l1(h - th));
        }
    }

    if (lane == 0) ws[wave] = contrib;
    __syncthreads();
    if (threadIdx.x == 0)
        atomicAdd(d_out, ws[0] + ws[1] + ws[2] + ws[3]);
}

extern "C" void kernel_launch(void* const* d_in, const int* in_sizes, int n_in,
                              void* d_out, int out_size, void* d_ws, size_t ws_size,
                              hipStream_t stream) {
    const float* out_p = (const float*)d_in[0];   // (128, 425, 28, 28)
    const float* tgt_p = (const float*)d_in[1];   // (128, 250)
    float* loss = (float*)d_out;

    int*   recIdx = (int*)d_ws;                   // NREC ints
    float* recF   = (float*)d_ws + NREC;          // 5 * NREC floats

    hipMemsetAsync(loss, 0, (size_t)out_size * sizeof(float), stream);

    prep_conf_loss<<<dim3(16, NBB), dim3(256), 0, stream>>>(
        out_p, tgt_p, recIdx, recF, loss);
    assigned_loss<<<dim3(NREC / 4), dim3(256), 0, stream>>>(
        out_p, recIdx, recF, loss);
}

// Round 3
// 235.260 us; speedup vs baseline: 1.1568x; 1.1370x over previous
//
#include <hip/hip_runtime.h>
#include <math.h>

#define NBB 128
#define NAA 5
#define NCC 80
#define NHH 28
#define NWW 28
#define NTT 50
#define CH  85            // 5 + NC
#define HW  784           // NH*NW
#define CELLS 3920        // NA*NH*NW

__constant__ float c_AW[5] = {2.8f, 5.1f, 6.4f, 9.2f, 14.1f};
__constant__ float c_AH[5] = {4.8f, 10.2f, 16.3f, 19.8f, 23.7f};

__device__ __forceinline__ float sigmoidf_(float x) {
    return 1.0f / (1.0f + __expf(-x));
}

__device__ __forceinline__ float smooth_l1(float d) {
    float ad = fabsf(d);
    return (ad < 1.0f) ? 0.5f * d * d : ad - 0.5f;
}

// ---------------------------------------------------------------------------
// Single fused kernel: grid (16, NB), block 256 (4 waves).
//
// Stage 1: threads 0..49 compute per-target records into LDS (cell, tconf,
//          tx/ty/tw/th/tcls) — redundant across the 16 x-blocks but trivial.
//          Dedup flag = "no later target hits the same cell" (numpy
//          last-write-wins scatter semantics).
// Stage 2: all 256 threads evaluate the confidence loss for their cell.
//          noobject mask via division-free test:
//          max_iou > 0.6  <=>  exists j: 1.6*inter_j > 0.6*(a1+a2_j).
//          assigned-cell scan (ascending j, last match wins) overrides.
// Stage 3: wave w of x-block bx owns record j = bx*4+w (64 slots >= 50):
//          focal 80-class loss (lanes = classes) + smooth-L1 coord loss.
// One atomicAdd per block carries conf partial + assigned contributions.
// ---------------------------------------------------------------------------
__global__ __launch_bounds__(256) void region_loss_fused(
    const float* __restrict__ out, const float* __restrict__ tgt,
    float* __restrict__ d_out)
{
    __shared__ float L2[NTT], R2[NTT], T2[NTT], B2[NTT], AR[NTT];
    __shared__ int   rCell[NTT];
    __shared__ float rTc[NTT], rTx[NTT], rTy[NTT], rTw[NTT], rTh[NTT];
    __shared__ int   rCls[NTT];
    __shared__ unsigned char rActive[NTT];
    __shared__ float red[256];
    __shared__ float waveS[4];

    const int b   = blockIdx.y;
    const int tid = threadIdx.x;

    // ---- Stage 1: per-target prep ----
    if (tid < NTT) {
        const float* tp = tgt + b * NTT * 5 + tid * 5;
        float cls = tp[0];
        float gx = tp[1] * NWW;
        float gy = tp[2] * NHH;
        float gw = tp[3] * NWW;
        float gh = tp[4] * NHH;
        float ga = gw * gh;

        L2[tid] = gx - gw * 0.5f;
        R2[tid] = gx + gw * 0.5f;
        T2[tid] = gy - gh * 0.5f;
        B2[tid] = gy + gh * 0.5f;
        AR[tid] = ga;

        // best anchor: IoU of (0,0,gw,gh) vs (0,0,aw,ah); first max wins
        int best = 0; float bestI = -1.0f;
        #pragma unroll
        for (int a = 0; a < 5; ++a) {
            float inter = fminf(gw, c_AW[a]) * fminf(gh, c_AH[a]);
            float uni   = ga + c_AW[a] * c_AH[a] - inter;
            float iou   = inter / uni;
            if (iou > bestI) { bestI = iou; best = a; }
        }
        int gi = (int)floorf(gx);
        int gj = (int)floorf(gy);
        int cell = (best * NHH + gj) * NWW + gi;

        // assigned predicted box (4 gathered loads)
        const float* op = out + ((size_t)(b * NAA + best) * CH) * HW + gj * NWW + gi;
        float px = sigmoidf_(op[0])      + (float)gi;
        float py = sigmoidf_(op[HW])     + (float)gj;
        float pw = __expf(op[2 * HW]) * c_AW[best];
        float ph = __expf(op[3 * HW]) * c_AH[best];

        float mx = fminf(px - pw * 0.5f, gx - gw * 0.5f);
        float Mx = fmaxf(px + pw * 0.5f, gx + gw * 0.5f);
        float my = fminf(py - ph * 0.5f, gy - gh * 0.5f);
        float My = fmaxf(py + ph * 0.5f, gy + gh * 0.5f);
        float cw  = pw + gw - (Mx - mx);
        float chh = ph + gh - (My - my);
        float inter = (cw > 0.f && chh > 0.f) ? cw * chh : 0.f;
        float uni   = pw * ph + ga - inter;

        rCell[tid] = cell;
        rTc[tid]   = inter / uni;
        rTx[tid]   = gx - (float)gi;
        rTy[tid]   = gy - (float)gj;
        rTw[tid]   = __logf(gw / c_AW[best]);
        rTh[tid]   = __logf(gh / c_AH[best]);
        rCls[tid]  = (int)cls;
    }
    __syncthreads();

    if (tid < NTT) {
        int cell = rCell[tid];
        unsigned char active = 1;
        for (int t2 = tid + 1; t2 < NTT; ++t2)
            if (rCell[t2] == cell) active = 0;   // later record wins
        rActive[tid] = active;
    }

    // ---- Stage 2: conf loss over cells ----
    const int cell = blockIdx.x * 256 + tid;
    float term = 0.0f;

    if (cell < CELLS) {
        int a  = cell / HW;
        int hw = cell - a * HW;
        int wi = hw % NWW;
        int hj = hw / NWW;
        const float* op = out + ((size_t)(b * NAA + a) * CH) * HW + hw;

        float px   = sigmoidf_(op[0])  + (float)wi;
        float py   = sigmoidf_(op[HW]) + (float)hj;
        float pw   = __expf(op[2 * HW]) * c_AW[a];
        float ph   = __expf(op[3 * HW]) * c_AH[a];
        float conf = sigmoidf_(op[4 * HW]);

        float l1 = px - pw * 0.5f, r1 = px + pw * 0.5f;
        float t1 = py - ph * 0.5f, b1 = py + ph * 0.5f;
        float a1 = pw * ph;

        bool flag = false;
        #pragma unroll 5
        for (int j = 0; j < NTT; ++j) {
            float cw  = fminf(r1, R2[j]) - fmaxf(l1, L2[j]);
            float chh = fminf(b1, B2[j]) - fmaxf(t1, T2[j]);
            float inter = (cw > 0.f && chh > 0.f) ? cw * chh : 0.f;
            flag = flag || (inter * 1.6f > 0.6f * (a1 + AR[j]));
        }

        bool assigned = false; float tc = 0.f;
        for (int j = 0; j < NTT; ++j) {
            if (rCell[j] == cell) { assigned = true; tc = rTc[j]; }  // last wins
        }

        if (assigned) { float d = conf - tc; term = 2.5f * d * d; }
        else if (!flag) { term = 0.5f * conf * conf; }
    }

    // ---- Stage 3: assigned-cell loss, one record per wave ----
    const int wave = tid >> 6;
    const int lane = tid & 63;
    const int j    = blockIdx.x * 4 + wave;   // 16*4 = 64 slots >= NTT
    float contrib = 0.0f;

    __syncthreads();   // rActive ready

    if (j < NTT && rActive[j]) {
        int rc = rCell[j];
        int a  = rc / HW;
        int hw = rc - a * HW;
        const float* op = out + ((size_t)(b * NAA + a) * CH) * HW + hw;

        // class logits: lane -> c=lane, plus c=64+lane for lane<16
        float l0 = op[(5 + lane) * HW];
        float l1 = (lane < 16) ? op[(5 + 64 + lane) * HW] : -INFINITY;

        float m = fmaxf(l0, l1);
        for (int o = 32; o >= 1; o >>= 1) m = fmaxf(m, __shfl_xor(m, o));
        float s = __expf(l0 - m) + ((lane < 16) ? __expf(l1 - m) : 0.0f);
        for (int o = 32; o >= 1; o >>= 1) s += __shfl_xor(s, o);

        int t = rCls[j];                              // wave-uniform
        float lt = (t < 64) ? __shfl(l0, t) : __shfl(l1, t - 64);
        float logpt = lt - m - __logf(s);
        float pt = __expf(logpt);
        float focal = -(1.0f - pt) * (1.0f - pt) * logpt;

        if (lane == 0) {
            float x = sigmoidf_(op[0]);
            float y = sigmoidf_(op[HW]);
            float w = op[2 * HW];
            float h = op[3 * HW];
            contrib = focal +
                      0.5f * (smooth_l1(x - rTx[j]) + smooth_l1(y - rTy[j]) +
                              smooth_l1(w - rTw[j]) + smooth_l1(h - rTh[j]));
        }
    }
    if (lane == 0) waveS[wave] = contrib;

    // ---- block reduction + single atomic ----
    red[tid] = term;
    __syncthreads();
    for (int s = 128; s > 0; s >>= 1) {
        if (tid < s) red[tid] += red[tid + s];
        __syncthreads();
    }
    if (tid == 0)
        atomicAdd(d_out, red[0] + waveS[0] + waveS[1] + waveS[2] + waveS[3]);
}

extern "C" void kernel_launch(void* const* d_in, const int* in_sizes, int n_in,
                              void* d_out, int out_size, void* d_ws, size_t ws_size,
                              hipStream_t stream) {
    const float* out_p = (const float*)d_in[0];   // (128, 425, 28, 28)
    const float* tgt_p = (const float*)d_in[1];   // (128, 250)
    float* loss = (float*)d_out;

    hipMemsetAsync(loss, 0, (size_t)out_size * sizeof(float), stream);

    region_loss_fused<<<dim3(16, NBB), dim3(256), 0, stream>>>(
        out_p, tgt_p, loss);
}